// Round 3
// baseline (543.603 us; speedup 1.0000x reference)
//
#include <hip/hip_runtime.h>
#include <hip/hip_cooperative_groups.h>

namespace cg = cooperative_groups;

#define B_    8
#define N_    2048
#define H_    512
#define K_    64
#define NROWS 16384            // B_*N_
#define RTOT  32768
#define NBLK  512
#define NTHR  256

typedef __attribute__((ext_vector_type(8))) __bf16 bf16x8;
typedef __attribute__((ext_vector_type(4))) float  floatx4;

#define MFMA(a, b, c) __builtin_amdgcn_mfma_f32_16x16x32_bf16((a), (b), (c), 0, 0, 0)

// One cooperative kernel, 512 blocks x 256 threads (2 waves/SIMD co-resident).
// Phase 0: W -> bf16 hi/lo; init minT to +inf.
// Phase 1: proj q/k = x@W^T+b via 3-pass hi/lo MFMA; emit bf16 hi/lo + row sumsq.
// Phase 2: min_m(qq+kk-2qk) per n; per-wave half-m sweep; atomicMin on float bits
//          as signed int (valid: dist >= -1e-4; tiny negatives still order OK).
// Phase 3: per block, w[b,:] = exp(-min) into LDS once; write 32 rows of out.
__global__ __launch_bounds__(NTHR, 2) void fused_kernel(
    const float* __restrict__ x, const float* __restrict__ y,
    const float* __restrict__ Wq, const float* __restrict__ bq,
    const float* __restrict__ Wk, const float* __restrict__ bk,
    float* __restrict__ out,
    __bf16* __restrict__ qh, __bf16* __restrict__ ql,
    float* __restrict__ sq, __bf16* __restrict__ Whilo,
    int* __restrict__ minT)
{
    cg::grid_group grid = cg::this_grid();
    const int tid  = threadIdx.x;
    const int blk  = blockIdx.x;
    const int gid  = blk * NTHR + tid;
    const int lane = tid & 63;
    const int quad = lane >> 4;
    const int l16  = lane & 15;

    // ---------------- phase 0: W hi/lo + minT init ----------------
    if (gid < 2 * 32768) {
        const bool isQ = gid < 32768;
        const int off  = isQ ? gid : gid - 32768;
        const float f  = isQ ? Wq[off] : Wk[off];
        const __bf16 h = (__bf16)f;
        const __bf16 l = (__bf16)(f - (float)h);
        const int base = isQ ? 0 : 65536;
        Whilo[base + off]         = h;
        Whilo[base + 32768 + off] = l;
    }
    if (gid < NROWS) minT[gid] = 0x7f800000;   // +inf bits (positive int)
    grid.sync();

    // ---------------- phase 1: projections ----------------
    {
        const int wid = gid >> 6;                 // 0..2047, 16 rows each
        const int rowbase = wid * 16;             // [0, 32768)
        const bool isQ = rowbase < NROWS;
        const float* __restrict__ X = isQ ? x : y;
        const int xrow0 = isQ ? rowbase : rowbase - NROWS;
        const __bf16* __restrict__ Whi = Whilo + (isQ ? 0 : 65536);
        const __bf16* __restrict__ Wlo = Whi + 32768;
        const float* __restrict__ bias = isQ ? bq : bk;

        floatx4 acc[4];
        #pragma unroll
        for (int ot = 0; ot < 4; ++ot) acc[ot] = floatx4{0.f, 0.f, 0.f, 0.f};

        for (int it = 0; it < 16; ++it) {
            const int k0 = it * 32 + quad * 8;
            const float4 f0 = *reinterpret_cast<const float4*>(
                &X[(size_t)(xrow0 + l16) * H_ + k0]);
            const float4 f1 = *reinterpret_cast<const float4*>(
                &X[(size_t)(xrow0 + l16) * H_ + k0 + 4]);
            const float fv[8] = {f0.x, f0.y, f0.z, f0.w, f1.x, f1.y, f1.z, f1.w};
            bf16x8 ahi, alo;
            #pragma unroll
            for (int j = 0; j < 8; ++j) {
                const __bf16 h = (__bf16)fv[j];
                ahi[j] = h;
                alo[j] = (__bf16)(fv[j] - (float)h);
            }
            #pragma unroll
            for (int ot = 0; ot < 4; ++ot) {
                const int wrow = ot * 16 + l16;
                const bf16x8 bhi = *reinterpret_cast<const bf16x8*>(
                    &Whi[(size_t)wrow * H_ + k0]);
                const bf16x8 blo = *reinterpret_cast<const bf16x8*>(
                    &Wlo[(size_t)wrow * H_ + k0]);
                acc[ot] = MFMA(ahi, bhi, acc[ot]);
                acc[ot] = MFMA(ahi, blo, acc[ot]);
                acc[ot] = MFMA(alo, bhi, acc[ot]);
            }
        }

        float ss[4] = {0.f, 0.f, 0.f, 0.f};
        #pragma unroll
        for (int ot = 0; ot < 4; ++ot) {
            const float bv = bias[ot * 16 + l16];
            #pragma unroll
            for (int r = 0; r < 4; ++r) {
                const float qv = acc[ot][r] + bv;
                acc[ot][r] = qv;
                ss[r] = fmaf(qv, qv, ss[r]);
            }
        }
        #pragma unroll
        for (int off = 1; off < 16; off <<= 1)
            #pragma unroll
            for (int r = 0; r < 4; ++r)
                ss[r] += __shfl_xor(ss[r], off);

        const int row0 = rowbase + quad * 4;      // + r
        if (l16 == 0) {
            #pragma unroll
            for (int r = 0; r < 4; ++r) sq[row0 + r] = ss[r];
        }
        #pragma unroll
        for (int ot = 0; ot < 4; ++ot)
            #pragma unroll
            for (int r = 0; r < 4; ++r) {
                const size_t idx = (size_t)(row0 + r) * K_ + ot * 16 + l16;
                const float qv = acc[ot][r];
                const __bf16 h = (__bf16)qv;
                qh[idx] = h;
                ql[idx] = (__bf16)(qv - (float)h);
            }
    }
    __threadfence();
    grid.sync();

    // ---------------- phase 2: min-distance sweep ----------------
    {
        const int wid  = gid >> 6;                // 0..2047
        const int t    = wid >> 1;                // n-tile 0..1023 (16 rows)
        const int half = wid & 1;                 // m half: [0,1024) or [1024,2048)
        const int b    = t >> 7;                  // 128 n-tiles per batch
        const int nrow = (t & 127) * 16;

        const size_t qrow = (size_t)(b * N_ + nrow + l16);
        const bf16x8 ahi0 = *reinterpret_cast<const bf16x8*>(&qh[qrow * K_ + quad * 8]);
        const bf16x8 ahi1 = *reinterpret_cast<const bf16x8*>(&qh[qrow * K_ + 32 + quad * 8]);
        const bf16x8 alo0 = *reinterpret_cast<const bf16x8*>(&ql[qrow * K_ + quad * 8]);
        const bf16x8 alo1 = *reinterpret_cast<const bf16x8*>(&ql[qrow * K_ + 32 + quad * 8]);

        const __bf16* __restrict__ kh = qh + (size_t)NROWS * K_;
        const __bf16* __restrict__ kl = ql + (size_t)NROWS * K_;
        const float*  __restrict__ kk = sq + NROWS;

        floatx4 runmin = floatx4{1e30f, 1e30f, 1e30f, 1e30f};
        const int ms0 = half * 64;

        #pragma unroll 2
        for (int ms = 0; ms < 64; ++ms) {
            const size_t krow = (size_t)(b * N_ + (ms0 + ms) * 16 + l16);
            const bf16x8 bh0 = *reinterpret_cast<const bf16x8*>(&kh[krow * K_ + quad * 8]);
            const bf16x8 bh1 = *reinterpret_cast<const bf16x8*>(&kh[krow * K_ + 32 + quad * 8]);
            const bf16x8 bl0 = *reinterpret_cast<const bf16x8*>(&kl[krow * K_ + quad * 8]);
            const bf16x8 bl1 = *reinterpret_cast<const bf16x8*>(&kl[krow * K_ + 32 + quad * 8]);
            const float kkv = kk[b * N_ + (ms0 + ms) * 16 + l16];

            floatx4 acc = floatx4{0.f, 0.f, 0.f, 0.f};
            acc = MFMA(ahi0, bh0, acc);
            acc = MFMA(ahi1, bh1, acc);
            acc = MFMA(ahi0, bl0, acc);
            acc = MFMA(ahi1, bl1, acc);
            acc = MFMA(alo0, bh0, acc);
            acc = MFMA(alo1, bh1, acc);

            #pragma unroll
            for (int r = 0; r < 4; ++r)
                runmin[r] = fminf(runmin[r], fmaf(-2.f, acc[r], kkv));
        }

        #pragma unroll
        for (int off = 1; off < 16; off <<= 1)
            #pragma unroll
            for (int r = 0; r < 4; ++r)
                runmin[r] = fminf(runmin[r], __shfl_xor(runmin[r], off));

        if (l16 == 0) {
            #pragma unroll
            for (int r = 0; r < 4; ++r) {
                const int row = nrow + quad * 4 + r;
                const float d = runmin[r] + sq[b * N_ + row];
                atomicMin(&minT[b * N_ + row], __float_as_int(d));
            }
        }
    }
    __threadfence();
    grid.sync();

    // ---------------- phase 3: exp + outer-product write ----------------
    {
        __shared__ float wl[2048];
        const int R0 = blk * 32;                  // 32 out-rows per block
        const int b  = R0 >> 11;
        const int n0 = R0 & 2047;
        for (int i = tid; i < 2048; i += NTHR)
            wl[i] = expf(-__int_as_float(minT[b * N_ + i]));
        __syncthreads();

        float4* __restrict__ out4 = reinterpret_cast<float4*>(out);
        for (int idx = tid; idx < 32 * 512; idx += NTHR) {
            const int row = idx >> 9;
            const int m4  = idx & 511;
            const float  wn = wl[n0 + row];
            const float4 wv = *reinterpret_cast<const float4*>(&wl[m4 * 4]);
            float4 o;
            o.x = wn * wv.x; o.y = wn * wv.y; o.z = wn * wv.z; o.w = wn * wv.w;
            out4[(size_t)(b * N_ + n0 + row) * 512 + m4] = o;
        }
    }
}

// ---------------------------------------------------------------------------
extern "C" void kernel_launch(void* const* d_in, const int* in_sizes, int n_in,
                              void* d_out, int out_size, void* d_ws, size_t ws_size,
                              hipStream_t stream)
{
    const float* x  = (const float*)d_in[0];
    const float* y  = (const float*)d_in[1];
    const float* Wq = (const float*)d_in[2];
    const float* bq = (const float*)d_in[3];
    const float* Wk = (const float*)d_in[4];
    const float* bk = (const float*)d_in[5];
    float* out = (float*)d_out;

    char* ws = (char*)d_ws;
    __bf16* qh    = (__bf16*)ws;                          // 4 MiB
    __bf16* ql    = (__bf16*)(ws + (4u << 20));           // 4 MiB
    float*  sq    = (float*)(ws + (8u << 20));            // 128 KiB
    __bf16* Whilo = (__bf16*)(ws + (8u << 20) + 131072);  // 256 KiB
    int*    minT  = (int*)  (ws + (8u << 20) + 393216);   // 64 KiB

    void* args[] = { (void*)&x, (void*)&y, (void*)&Wq, (void*)&bq,
                     (void*)&Wk, (void*)&bk, (void*)&out,
                     (void*)&qh, (void*)&ql, (void*)&sq,
                     (void*)&Whilo, (void*)&minT };
    hipLaunchCooperativeKernel((void*)fused_kernel, dim3(NBLK), dim3(NTHR),
                               args, 0, stream);
}